// Round 2
// baseline (940.757 us; speedup 1.0000x reference)
//
#include <hip/hip_runtime.h>
#include <math.h>

#define C 256
#define S 16
#define CR 64
#define NREP 16        // replicated global accumulators (atomic contention /16)

// ---------------- Kernel 1: segment sums + counts, register-resident ---------
// One wave per row, lane l owns channels 4l..4l+3 (float4 = 16 B/lane).
// Segment id is wave-uniform -> readfirstlane + scalar 16-way switch selects a
// compile-time-indexed float4 register accumulator. No LDS, no RMW chain.
__global__ __launch_bounds__(256) void k_segsum(
    const float* __restrict__ x, const int* __restrict__ idx,
    float* __restrict__ psum, int* __restrict__ pcnt, int nrows)
{
    const int lane = threadIdx.x & 63;
    const int wid  = __builtin_amdgcn_readfirstlane(
                        (blockIdx.x * blockDim.x + threadIdx.x) >> 6);
    const int nw   = (gridDim.x * blockDim.x) >> 6;   // total waves

    float4 a0={0,0,0,0},a1={0,0,0,0},a2={0,0,0,0},a3={0,0,0,0},
           a4={0,0,0,0},a5={0,0,0,0},a6={0,0,0,0},a7={0,0,0,0},
           a8={0,0,0,0},a9={0,0,0,0},a10={0,0,0,0},a11={0,0,0,0},
           a12={0,0,0,0},a13={0,0,0,0},a14={0,0,0,0},a15={0,0,0,0};
    int c0=0,c1=0,c2=0,c3=0,c4=0,c5=0,c6=0,c7=0,
        c8=0,c9=0,c10=0,c11=0,c12=0,c13=0,c14=0,c15=0;

    const float4* __restrict__ x4 = reinterpret_cast<const float4*>(x);

    // depth-2 software pipeline: rows r, r+nw in flight while processing r
    int   row = wid;
    bool  p0 = row < nrows;
    float4 v0 = {0,0,0,0}; int s0 = 0;
    if (p0) { v0 = x4[row * (C/4) + lane]; s0 = idx[row]; }
    int   rowN = row + nw;
    bool  p1 = rowN < nrows;
    float4 v1 = {0,0,0,0}; int s1 = 0;
    if (p1) { v1 = x4[rowN * (C/4) + lane]; s1 = idx[rowN]; }

    while (p0) {
        const int rowP = rowN + nw;
        const bool p2 = rowP < nrows;
        float4 v2 = {0,0,0,0}; int s2 = 0;
        if (p2) { v2 = x4[rowP * (C/4) + lane]; s2 = idx[rowP]; }

        #define ACASE(K) case K: a##K.x+=v0.x; a##K.y+=v0.y; a##K.z+=v0.z; a##K.w+=v0.w; c##K++; break;
        switch (__builtin_amdgcn_readfirstlane(s0)) {
            ACASE(0)  ACASE(1)  ACASE(2)  ACASE(3)
            ACASE(4)  ACASE(5)  ACASE(6)  ACASE(7)
            ACASE(8)  ACASE(9)  ACASE(10) ACASE(11)
            ACASE(12) ACASE(13) ACASE(14) ACASE(15)
        }
        #undef ACASE

        v0 = v1; s0 = s1; p0 = p1;
        v1 = v2; s1 = s2; p1 = p2;
        rowN = rowP;
    }

    // flush: 64 atomicAdds/lane into this wave's replica
    const int rep = wid & (NREP - 1);
    float* gs = psum + rep * S * C;
    int*   gc = pcnt + rep * S;
    #define FLUSH(K) { float* p = gs + K * C + 4 * lane; \
        atomicAdd(p + 0, a##K.x); atomicAdd(p + 1, a##K.y); \
        atomicAdd(p + 2, a##K.z); atomicAdd(p + 3, a##K.w); \
        if (lane == 0 && c##K) atomicAdd(&gc[K], c##K); }
    FLUSH(0)  FLUSH(1)  FLUSH(2)  FLUSH(3)
    FLUSH(4)  FLUSH(5)  FLUSH(6)  FLUSH(7)
    FLUSH(8)  FLUSH(9)  FLUSH(10) FLUSH(11)
    FLUSH(12) FLUSH(13) FLUSH(14) FLUSH(15)
    #undef FLUSH
}

// ---------------- Kernel 2: reduce replicas + tiny SE MLP ----------------
__global__ __launch_bounds__(256) void k_mlp(
    const float* __restrict__ psum, const int* __restrict__ pcnt,
    const float* __restrict__ w1, const float* __restrict__ w2,
    float* __restrict__ gate)
{
    __shared__ float sm[S][C];
    __shared__ float h[S][CR];
    __shared__ float cnt[S];
    const int t = threadIdx.x;

    if (t < S) {
        int c = 0;
        #pragma unroll
        for (int r = 0; r < NREP; r++) c += pcnt[r * S + t];
        cnt[t] = fmaxf((float)c, 1.0f);
    }
    __syncthreads();

    for (int i = t; i < S * C; i += 256) {
        float v = 0.0f;
        #pragma unroll
        for (int r = 0; r < NREP; r++) v += psum[r * S * C + i];
        sm[i / C][i % C] = v / cnt[i / C];
    }
    __syncthreads();

    for (int o = t; o < S * CR; o += 256) {
        const int s = o / CR, j = o % CR;
        float acc = 0.0f;
        #pragma unroll 4
        for (int k = 0; k < C; k++) acc += sm[s][k] * w1[k * CR + j];
        h[s][j] = fmaxf(acc, 0.0f);
    }
    __syncthreads();

    for (int o = t; o < S * C; o += 256) {
        const int s = o / C, j = o % C;
        float acc = 0.0f;
        #pragma unroll
        for (int k = 0; k < CR; k++) acc += h[s][k] * w2[k * C + j];
        gate[o] = 1.0f / (1.0f + expf(-acc));
    }
}

// ---------------- Kernel 3: out = x * gate[idx], 2 rows/wave/iter ------------
__global__ __launch_bounds__(256) void k_mod(
    const float* __restrict__ x, const int* __restrict__ idx,
    const float* __restrict__ gate, float* __restrict__ out, int nrows)
{
    const int l  = threadIdx.x & 63;
    const int w  = threadIdx.x >> 6;
    const int gw = blockIdx.x * 4 + w;      // global wave id
    const int nw = gridDim.x * 4;
    const float4* __restrict__ x4 = reinterpret_cast<const float4*>(x);
    const float4* __restrict__ g4 = reinterpret_cast<const float4*>(gate);
    float4* __restrict__ o4 = reinterpret_cast<float4*>(out);

    for (int row = gw; row < nrows; row += 2 * nw) {
        const int r2 = row + nw;
        const bool has2 = r2 < nrows;
        const int sA = idx[row];
        float4 vA = x4[row * (C/4) + l];
        int sB = 0; float4 vB = {0,0,0,0};
        if (has2) { sB = idx[r2]; vB = x4[r2 * (C/4) + l]; }

        const float4 gA = g4[sA * (C/4) + l];
        vA.x *= gA.x; vA.y *= gA.y; vA.z *= gA.z; vA.w *= gA.w;
        o4[row * (C/4) + l] = vA;

        if (has2) {
            const float4 gB = g4[sB * (C/4) + l];
            vB.x *= gB.x; vB.y *= gB.y; vB.z *= gB.z; vB.w *= gB.w;
            o4[r2 * (C/4) + l] = vB;
        }
    }
}

extern "C" void kernel_launch(void* const* d_in, const int* in_sizes, int n_in,
                              void* d_out, int out_size, void* d_ws, size_t ws_size,
                              hipStream_t stream)
{
    const float* x   = (const float*)d_in[0];
    const int*   idx = (const int*)  d_in[1];
    const float* w1  = (const float*)d_in[2];
    const float* w2  = (const float*)d_in[3];
    float* out = (float*)d_out;
    const int nrows = in_sizes[1];

    // ws: [psum: NREP*S*C f32][pcnt: NREP*S i32][gate: S*C f32]
    float* psum = (float*)d_ws;
    int*   pcnt = (int*)(psum + NREP * S * C);
    float* gate = (float*)(pcnt + NREP * S);

    const size_t zero_bytes = NREP * S * C * sizeof(float) + NREP * S * sizeof(int);
    hipMemsetAsync(d_ws, 0, zero_bytes, stream);

    k_segsum<<<1024, 256, 0, stream>>>(x, idx, psum, pcnt, nrows);
    k_mlp<<<1, 256, 0, stream>>>(psum, pcnt, w1, w2, gate);
    k_mod<<<2048, 256, 0, stream>>>(x, idx, gate, out, nrows);
}